// Round 9
// baseline (610.214 us; speedup 1.0000x reference)
//
#include <hip/hip_runtime.h>

typedef short short8 __attribute__((ext_vector_type(8)));
typedef float floatx4 __attribute__((ext_vector_type(4)));

#define GPB 8        // graphs per block (consecutive in sorted order)
#define ORD_CAP 2368 // preloaded order[] entries; also pushes LDS > 80KB so only
                     // 1 block/CU fits -> compiler budgets 256 VGPR (no spill)

__device__ __forceinline__ unsigned short f2bf(float x) {
  union { float f; unsigned int u; } c; c.f = x;
  return (unsigned short)((c.u + 0x7FFFu + ((c.u >> 16) & 1u)) >> 16);
}

__device__ __forceinline__ unsigned cvtpk(float lo, float hi) {
  unsigned r;
  asm("v_cvt_pk_bf16_f32 %0, %1, %2" : "=v"(r) : "v"(lo), "v"(hi));
  return r;
}

__global__ void k_hist(const int* __restrict__ gid, int L, int* __restrict__ counts) {
  int i = blockIdx.x * blockDim.x + threadIdx.x;
  if (i < L) atomicAdd(&counts[gid[i]], 1);
}

__global__ void k_scan(const int* __restrict__ counts, int* __restrict__ offsets,
                       int* __restrict__ cursor, int G) {
  __shared__ int sc[1024];
  int t = threadIdx.x;
  int items = (G + 1023) >> 10;
  int base = t * items;
  int s = 0;
  for (int i = 0; i < items; ++i) { int idx = base + i; if (idx < G) s += counts[idx]; }
  sc[t] = s;
  __syncthreads();
  for (int off = 1; off < 1024; off <<= 1) {
    int v = (t >= off) ? sc[t - off] : 0;
    __syncthreads();
    if (t >= off) sc[t] += v;
    __syncthreads();
  }
  int run = (t == 0) ? 0 : sc[t - 1];
  for (int i = 0; i < items; ++i) {
    int idx = base + i;
    if (idx < G) { offsets[idx] = run; cursor[idx] = run; run += counts[idx]; }
  }
  if (t == 1023) offsets[G] = sc[1023];
}

__global__ void k_scatter(const int* __restrict__ gid, int L, int* __restrict__ cursor,
                          int* __restrict__ order) {
  int i = blockIdx.x * blockDim.x + threadIdx.x;
  if (i < L) {
    int g = gid[i];
    int pos = atomicAdd(&cursor[g], 1);
    order[pos] = i;
  }
}

// W2 [512][256] bf16, 8-wave layout: row j2 -> wv=j2>>6 (wave), half=(j2>>5)&1
// (0 key, 1 val), c=j2&31, d = 32*wv + c.
__global__ void k_prepw(const float* __restrict__ keyW, const float* __restrict__ valW,
                        unsigned short* __restrict__ W2) {
  int j2 = blockIdx.x;
  int k = threadIdx.x;
  int wv = j2 >> 6, half = (j2 >> 5) & 1, c = j2 & 31;
  int d = (wv << 5) + c;
  const float* src = half ? valW : keyW;
  W2[j2 * 256 + k] = f2bf(src[d * 256 + k]);
}

__launch_bounds__(512, 1)
__global__ void k_fused(const float* __restrict__ fnode,
                        const unsigned short* __restrict__ W2,
                        const float* __restrict__ key_b, const float* __restrict__ value_b,
                        const float* __restrict__ gamma, const float* __restrict__ beta,
                        const int* __restrict__ order, const int* __restrict__ offsets,
                        float* __restrict__ out, int L, int Gtot) {
  // bf16 A tile, double-buffered: 64 rows x 512B. Logical 16B-slot q of row r lives
  // at physical slot q ^ key(r), key(r) = (r&7) ^ ((r&8)>>1). Same XOR both sides.
  __shared__ __align__(16) unsigned short As[2][64 * 256];
  __shared__ int ord_s[ORD_CAP];   // 9.25KB: total LDS ~83.3KB > 80KB -> 1 block/CU
  __shared__ float fg[GPB][256];
  __shared__ int eb[GPB + 1];
  __shared__ float redS[4], redS2[4];

  const int t = threadIdx.x;
  const int lane = t & 63;
  const int w = t >> 6;        // wave 0..7 -> d range [32w, 32w+32)
  const int lcol = lane & 15;
  const int lrow = lane >> 4;
  const int g0 = blockIdx.x * GPB;

  if (t <= GPB) eb[t] = offsets[min(g0 + t, Gtot)];
  __syncthreads();
  const int rbase = eb[0];
  const int span = eb[GPB] - rbase;
  const int nc = max(1, (span + 63) >> 6);

  for (int i = t; i < ORD_CAP; i += 512) ord_s[i] = order[min(rbase + i, L - 1)];

  float kb[2], vb[2];
#pragma unroll
  for (int nj = 0; nj < 2; ++nj) {
    int d = (w << 5) + (nj << 4) + lcol;
    kb[nj] = key_b[d];
    vb[nj] = value_b[d];
  }
  const unsigned short* Wn[4];  // nj 0-1 key, 2-3 val (same d as nj-2)
#pragma unroll
  for (int nj = 0; nj < 4; ++nj)
    Wn[nj] = W2 + ((size_t)((w << 6) + ((nj >> 1) << 5) + ((nj & 1) << 4) + lcol)) * 256 +
             lrow * 8;
  short8 bp[4][6];  // kk 0..5 register-resident; kk 6..7 streamed from L2
#pragma unroll
  for (int nj = 0; nj < 4; ++nj)
#pragma unroll
    for (int kk = 0; kk < 6; ++kk)
      bp[nj][kk] = *reinterpret_cast<const short8*>(Wn[nj] + (kk << 5));

  __syncthreads();  // ord_s ready

  // ---- T14: issue gather into regs early; convert+ds_write late ----
  float4 fl[8];
  auto issue = [&](int c) {
#pragma unroll
    for (int it = 0; it < 8; ++it) {
      int gi = (c << 6) + (w << 3) + it;
      if (gi > span - 1) gi = span - 1;
      if (gi < 0) gi = 0;
      const int idx = (gi < ORD_CAP) ? ord_s[gi] : order[rbase + gi];
      fl[it] = *reinterpret_cast<const float4*>(fnode + (size_t)idx * 256 + (lane << 2));
    }
  };
  auto stwr = [&](int buf) {
#pragma unroll
    for (int it = 0; it < 8; ++it) {
      const int r = (w << 3) + it;
      const int kw = (r & 7) ^ ((r & 8) >> 1);
      uint2 v;
      v.x = cvtpk(fl[it].x, fl[it].y);
      v.y = cvtpk(fl[it].z, fl[it].w);
      char* p = (char*)&As[buf][0] + (r << 9) +
                ((((lane >> 1) ^ kw) << 4) | ((lane & 1) << 3));
      *reinterpret_cast<uint2*>(p) = v;
    }
  };

  issue(0);
  __builtin_amdgcn_sched_barrier(0);
  stwr(0);
  __syncthreads();

  int curg = 0, flushed = 0;
  int ecur = eb[1] - rbase;
  float den[2] = {0.f, 0.f};
  float num[2] = {0.f, 0.f};
  const int keyr = (lcol & 7) ^ ((lcol & 8) >> 1);  // frag-row XOR (row&15 == lcol)

  for (int c = 0; c < nc; ++c) {
    issue(c + 1 < nc ? c + 1 : c);  // clamped; last-iter result unused
    __builtin_amdgcn_sched_barrier(0);

    // ---- MFMA on tile c (A from LDS, B from registers + kk 6-7 from L2) ----
    const char* AsB = (const char*)&As[c & 1][0];
    floatx4 acc[4][4];
#pragma unroll
    for (int mi = 0; mi < 4; ++mi)
#pragma unroll
      for (int nj = 0; nj < 4; ++nj)
        acc[mi][nj] = (floatx4){0.f, 0.f, 0.f, 0.f};

    __builtin_amdgcn_s_setprio(1);
#pragma unroll
    for (int kk = 0; kk < 8; ++kk) {
      short8 afr[4];
#pragma unroll
      for (int mi = 0; mi < 4; ++mi) {
        const int row = mi * 16 + lcol;
        afr[mi] = *reinterpret_cast<const short8*>(
            AsB + (row << 9) + ((((kk << 2) | lrow) ^ keyr) << 4));
      }
#pragma unroll
      for (int nj = 0; nj < 4; ++nj) {
        const short8 bfr = (kk < 6)
                               ? bp[nj][kk]
                               : *reinterpret_cast<const short8*>(Wn[nj] + (kk << 5));
#pragma unroll
        for (int mi = 0; mi < 4; ++mi)
          acc[mi][nj] =
              __builtin_amdgcn_mfma_f32_16x16x32_bf16(afr[mi], bfr, acc[mi][nj], 0, 0, 0);
      }
    }
    __builtin_amdgcn_s_setprio(0);

    // ---- segmented epilogue (uniform run loop over graph boundaries) ----
    const int m0 = c << 6;
    {
      int lo = 0;
      while (true) {
        const int hi = min(ecur - m0, 64);
#pragma unroll
        for (int mi = 0; mi < 4; ++mi)
#pragma unroll
          for (int qq = 0; qq < 4; ++qq) {
            const int r = mi * 16 + lrow * 4 + qq;
            const bool in = (r >= lo) && (r < hi);
#pragma unroll
            for (int nj = 0; nj < 2; ++nj) {
              const float a = acc[mi][nj][qq] + kb[nj];
              const float v = acc[mi][nj + 2][qq] + vb[nj];
              const float e_ = in ? __expf(a) : 0.f;
              den[nj] += e_;
              num[nj] += v * e_;
            }
          }
        if (ecur <= m0 + 64) {
#pragma unroll
          for (int nj = 0; nj < 2; ++nj) {
            float ds = den[nj], ns = num[nj];
            ds += __shfl_xor(ds, 16, 64);
            ds += __shfl_xor(ds, 32, 64);
            ns += __shfl_xor(ns, 16, 64);
            ns += __shfl_xor(ns, 32, 64);
            if (lrow == 0)
              fg[curg & (GPB - 1)][(w << 5) + (nj << 4) + lcol] = ns / (ds + 1e-7f);
            den[nj] = 0.f;
            num[nj] = 0.f;
          }
          ++curg;
          lo = hi;
          ecur = (curg < GPB) ? (eb[curg + 1] - rbase) : 0x7fffffff;
        } else
          break;
        if (curg >= GPB) break;
      }
    }

    // ---- LayerNorm + store for graphs completed this chunk (uniform) ----
    if (curg > flushed) {
      __syncthreads();
      for (int j = flushed; j < curg; ++j) {
        float x = 0.f;
        if (t < 256) x = fg[j & (GPB - 1)][t];
        float s = x, s2 = x * x;
#pragma unroll
        for (int o = 32; o > 0; o >>= 1) {
          s += __shfl_xor(s, o, 64);
          s2 += __shfl_xor(s2, o, 64);
        }
        if (t < 256 && lane == 0) { redS[w] = s; redS2[w] = s2; }
        __syncthreads();
        if (t < 256 && (g0 + j) < Gtot) {
          const float ts = redS[0] + redS[1] + redS[2] + redS[3];
          const float ts2 = redS2[0] + redS2[1] + redS2[2] + redS2[3];
          const float mu = ts * (1.f / 256.f);
          const float var = ts2 * (1.f / 256.f) - mu * mu;
          const float inv = rsqrtf(var + 1e-5f);
          out[(size_t)(g0 + j) * 256 + t] = (x - mu) * inv * gamma[t] + beta[t];
        }
        __syncthreads();
      }
      flushed = curg;
    }

    stwr((c + 1) & 1);  // convert prefetched rows; loads drain here (hidden by MFMA)
    __syncthreads();    // next tile published; gates next overwrite of As[c&1]
  }
}

extern "C" void kernel_launch(void* const* d_in, const int* in_sizes, int n_in,
                              void* d_out, int out_size, void* d_ws, size_t ws_size,
                              hipStream_t stream) {
  const float* f_node   = (const float*)d_in[0];
  const float* key_W    = (const float*)d_in[1];
  const float* key_b    = (const float*)d_in[2];
  const float* value_W  = (const float*)d_in[3];
  const float* value_b  = (const float*)d_in[4];
  const float* gamma    = (const float*)d_in[5];
  const float* beta     = (const float*)d_in[6];
  const int*   graph_id = (const int*)d_in[7];
  const int L = in_sizes[0] / 256;
  const int G = out_size / 256;

  char* ws = (char*)d_ws;
  size_t off = 0;
  int* order = (int*)(ws + off); off += (size_t)L * 4;
  off = (off + 255) & ~(size_t)255;
  int* counts = (int*)(ws + off); off += (size_t)G * 4;
  int* offsets = (int*)(ws + off); off += (size_t)(G + 1) * 4;
  int* cursor = (int*)(ws + off); off += (size_t)G * 4;
  off = (off + 255) & ~(size_t)255;
  unsigned short* W2 = (unsigned short*)(ws + off); off += 512 * 256 * 2;

  hipMemsetAsync(counts, 0, (size_t)G * 4, stream);
  k_hist<<<(L + 255) / 256, 256, 0, stream>>>(graph_id, L, counts);
  k_scan<<<1, 1024, 0, stream>>>(counts, offsets, cursor, G);
  k_scatter<<<(L + 255) / 256, 256, 0, stream>>>(graph_id, L, cursor, order);
  k_prepw<<<512, 256, 0, stream>>>(key_W, value_W, W2);
  const int nblk = (G + GPB - 1) / GPB;
  k_fused<<<nblk, 512, 0, stream>>>(f_node, W2, key_b, value_b, gamma, beta, order,
                                    offsets, (float*)d_out, L, G);
}

// Round 10
// 424.652 us; speedup vs baseline: 1.4370x; 1.4370x over previous
//
#include <hip/hip_runtime.h>

typedef short short8 __attribute__((ext_vector_type(8)));
typedef float floatx4 __attribute__((ext_vector_type(4)));

#define GPB 16       // graphs per block -> 256 blocks, exactly 1 resident per CU
#define ORD_CAP 2304 // preloaded order[] entries (span ~1953 +- 44; ~8 sigma headroom)

__device__ __forceinline__ unsigned short f2bf(float x) {
  union { float f; unsigned int u; } c; c.f = x;
  return (unsigned short)((c.u + 0x7FFFu + ((c.u >> 16) & 1u)) >> 16);
}

__device__ __forceinline__ unsigned cvtpk(float lo, float hi) {
  unsigned r;
  asm("v_cvt_pk_bf16_f32 %0, %1, %2" : "=v"(r) : "v"(lo), "v"(hi));
  return r;
}

__device__ __forceinline__ void gld16(const void* g, void* l) {
  __builtin_amdgcn_global_load_lds((const __attribute__((address_space(1))) void*)g,
                                   (__attribute__((address_space(3))) void*)l, 16, 0, 0);
}

__global__ void k_hist(const int* __restrict__ gid, int L, int* __restrict__ counts) {
  int i = blockIdx.x * blockDim.x + threadIdx.x;
  if (i < L) atomicAdd(&counts[gid[i]], 1);
}

__global__ void k_scan(const int* __restrict__ counts, int* __restrict__ offsets,
                       int* __restrict__ cursor, int G) {
  __shared__ int sc[1024];
  int t = threadIdx.x;
  int items = (G + 1023) >> 10;
  int base = t * items;
  int s = 0;
  for (int i = 0; i < items; ++i) { int idx = base + i; if (idx < G) s += counts[idx]; }
  sc[t] = s;
  __syncthreads();
  for (int off = 1; off < 1024; off <<= 1) {
    int v = (t >= off) ? sc[t - off] : 0;
    __syncthreads();
    if (t >= off) sc[t] += v;
    __syncthreads();
  }
  int run = (t == 0) ? 0 : sc[t - 1];
  for (int i = 0; i < items; ++i) {
    int idx = base + i;
    if (idx < G) { offsets[idx] = run; cursor[idx] = run; run += counts[idx]; }
  }
  if (t == 1023) offsets[G] = sc[1023];
}

__global__ void k_scatter(const int* __restrict__ gid, int L, int* __restrict__ cursor,
                          int* __restrict__ order) {
  int i = blockIdx.x * blockDim.x + threadIdx.x;
  if (i < L) {
    int g = gid[i];
    int pos = atomicAdd(&cursor[g], 1);
    order[pos] = i;
  }
}

// W2 [512][256] bf16, 8-wave layout: row j2 -> wv=j2>>6 (wave), half=(j2>>5)&1
// (0 key, 1 val), c=j2&31, d = 32*wv + c.
__global__ void k_prepw(const float* __restrict__ keyW, const float* __restrict__ valW,
                        unsigned short* __restrict__ W2) {
  int j2 = blockIdx.x;
  int k = threadIdx.x;
  int wv = j2 >> 6, half = (j2 >> 5) & 1, c = j2 & 31;
  int d = (wv << 5) + c;
  const float* src = half ? valW : keyW;
  W2[j2 * 256 + k] = f2bf(src[d * 256 + k]);
}

__launch_bounds__(512, 1)
__global__ void k_fused(const float* __restrict__ fnode,
                        const unsigned short* __restrict__ W2,
                        const float* __restrict__ key_b, const float* __restrict__ value_b,
                        const float* __restrict__ gamma, const float* __restrict__ beta,
                        const int* __restrict__ order, const int* __restrict__ offsets,
                        float* __restrict__ out, int L, int Gtot) {
  // A dbuf: 2 x (64 rows x 1KB f32), filled by global_load_lds.
  // LDS 16B-slot s of row r holds global slot s ^ (r&7) (source-side XOR swizzle).
  __shared__ __align__(16) float As[2][64 * 256];
  __shared__ int ord_s[ORD_CAP];
  __shared__ float fg[GPB][256];
  __shared__ int eb[GPB + 1];
  __shared__ float redS[4], redS2[4];

  const int t = threadIdx.x;
  const int lane = t & 63;
  const int w = t >> 6;        // wave 0..7 -> d range [32w, 32w+32)
  const int lcol = lane & 15;
  const int lrow = lane >> 4;
  const int g0 = blockIdx.x * GPB;

  if (t <= GPB) eb[t] = offsets[min(g0 + t, Gtot)];
  __syncthreads();
  const int rbase = eb[0];
  const int span = eb[GPB] - rbase;
  const int nc = max(1, (span + 63) >> 6);

  for (int i = t; i < ORD_CAP; i += 512) ord_s[i] = order[min(rbase + i, L - 1)];

  float kb[2], vb[2];
#pragma unroll
  for (int nj = 0; nj < 2; ++nj) {
    int d = (w << 5) + (nj << 4) + lcol;
    kb[nj] = key_b[d];
    vb[nj] = value_b[d];
  }
  const unsigned short* Wn[4];  // nj 0-1 key, 2-3 val (same d as nj-2)
#pragma unroll
  for (int nj = 0; nj < 4; ++nj)
    Wn[nj] = W2 + ((size_t)((w << 6) + ((nj >> 1) << 5) + ((nj & 1) << 4) + lcol)) * 256 +
             lrow * 8;
  short8 bp[4][4];  // kk 0..3 register-resident; kk 4..7 streamed from L2
#pragma unroll
  for (int nj = 0; nj < 4; ++nj)
#pragma unroll
    for (int kk = 0; kk < 4; ++kk)
      bp[nj][kk] = *reinterpret_cast<const short8*>(Wn[nj] + (kk << 5));

  __syncthreads();  // ord_s ready

  // stage chunk c into buffer buf: wave w gathers rows [8w, 8w+8), 1KB row per gld16x64
  auto stage = [&](int c, int buf) {
    const int m0 = c << 6;
#pragma unroll
    for (int it = 0; it < 8; ++it) {
      int gi = m0 + (w << 3) + it;
      if (gi > span - 1) gi = span - 1;
      const int idx = (gi < ORD_CAP) ? ord_s[gi] : order[rbase + gi];
      const char* gsrc =
          (const char*)fnode + ((size_t)idx << 10) + ((lane << 4) ^ (it << 4));
      gld16(gsrc, (char*)&As[buf][0] + (((w << 3) + it) << 10));
    }
  };

  stage(0, 0);
  if (nc > 1) {
    stage(1, 1);
    asm volatile("s_waitcnt vmcnt(8)" ::: "memory");  // chunk 0's 8 gld retired (FIFO)
  } else {
    asm volatile("s_waitcnt vmcnt(0)" ::: "memory");
  }
  __builtin_amdgcn_s_barrier();

  int curg = 0, flushed = 0;
  int ecur = eb[1] - rbase;
  float den[2] = {0.f, 0.f};
  float num[2] = {0.f, 0.f};

  for (int c = 0; c < nc; ++c) {
    // ---- MFMA on chunk c (A from LDS f32->bf16 at frag load; B regs + kk4-7 L2) ----
    const char* AsB = (const char*)&As[c & 1][0];
    floatx4 acc[4][4];
#pragma unroll
    for (int mi = 0; mi < 4; ++mi)
#pragma unroll
      for (int nj = 0; nj < 4; ++nj)
        acc[mi][nj] = (floatx4){0.f, 0.f, 0.f, 0.f};

    __builtin_amdgcn_s_setprio(1);
#pragma unroll
    for (int kk = 0; kk < 8; ++kk) {
      short8 afr[4];
#pragma unroll
      for (int mi = 0; mi < 4; ++mi) {
        const int row = mi * 16 + lcol;
        const int x7 = row & 7;
        const int s0 = (kk * 8 + lrow * 2) ^ x7;
        const int s1 = (kk * 8 + lrow * 2 + 1) ^ x7;
        const floatx4 lo = *reinterpret_cast<const floatx4*>(AsB + (row << 10) + (s0 << 4));
        const floatx4 hi = *reinterpret_cast<const floatx4*>(AsB + (row << 10) + (s1 << 4));
        union { unsigned u[4]; short8 s; } cc;
        cc.u[0] = cvtpk(lo[0], lo[1]);
        cc.u[1] = cvtpk(lo[2], lo[3]);
        cc.u[2] = cvtpk(hi[0], hi[1]);
        cc.u[3] = cvtpk(hi[2], hi[3]);
        afr[mi] = cc.s;
      }
#pragma unroll
      for (int nj = 0; nj < 4; ++nj) {
        const short8 bfr = (kk < 4)
                               ? bp[nj][kk]
                               : *reinterpret_cast<const short8*>(Wn[nj] + (kk << 5));
#pragma unroll
        for (int mi = 0; mi < 4; ++mi)
          acc[mi][nj] =
              __builtin_amdgcn_mfma_f32_16x16x32_bf16(afr[mi], bfr, acc[mi][nj], 0, 0, 0);
      }
    }
    __builtin_amdgcn_s_setprio(0);

    // ---- segmented epilogue (uniform run loop over graph boundaries) ----
    const int m0 = c << 6;
    {
      int lo = 0;
      while (true) {
        const int hi = min(ecur - m0, 64);
#pragma unroll
        for (int mi = 0; mi < 4; ++mi)
#pragma unroll
          for (int qq = 0; qq < 4; ++qq) {
            const int r = mi * 16 + lrow * 4 + qq;
            const bool in = (r >= lo) && (r < hi);
#pragma unroll
            for (int nj = 0; nj < 2; ++nj) {
              const float a = acc[mi][nj][qq] + kb[nj];
              const float v = acc[mi][nj + 2][qq] + vb[nj];
              const float e_ = in ? __expf(a) : 0.f;
              den[nj] += e_;
              num[nj] += v * e_;
            }
          }
        if (ecur <= m0 + 64) {
#pragma unroll
          for (int nj = 0; nj < 2; ++nj) {
            float ds = den[nj], ns = num[nj];
            ds += __shfl_xor(ds, 16, 64);
            ds += __shfl_xor(ds, 32, 64);
            ns += __shfl_xor(ns, 16, 64);
            ns += __shfl_xor(ns, 32, 64);
            if (lrow == 0)
              fg[curg & (GPB - 1)][(w << 5) + (nj << 4) + lcol] = ns / (ds + 1e-7f);
            den[nj] = 0.f;
            num[nj] = 0.f;
          }
          ++curg;
          lo = hi;
          ecur = (curg < GPB) ? (eb[curg + 1] - rbase) : 0x7fffffff;
        } else
          break;
        if (curg >= GPB) break;
      }
    }

    // ---- LayerNorm + store for completed graphs (raw barriers: no vmcnt drain) ----
    if (curg > flushed) {
      asm volatile("s_waitcnt lgkmcnt(0)" ::: "memory");
      __builtin_amdgcn_s_barrier();  // fg writes visible
      for (int j = flushed; j < curg; ++j) {
        float x = 0.f;
        if (t < 256) x = fg[j & (GPB - 1)][t];
        float s = x, s2 = x * x;
#pragma unroll
        for (int o = 32; o > 0; o >>= 1) {
          s += __shfl_xor(s, o, 64);
          s2 += __shfl_xor(s2, o, 64);
        }
        if (t < 256 && lane == 0) { redS[w] = s; redS2[w] = s2; }
        asm volatile("s_waitcnt lgkmcnt(0)" ::: "memory");
        __builtin_amdgcn_s_barrier();  // redS visible
        if (t < 256 && (g0 + j) < Gtot) {
          const float ts = redS[0] + redS[1] + redS[2] + redS[3];
          const float ts2 = redS2[0] + redS2[1] + redS2[2] + redS2[3];
          const float mu = ts * (1.f / 256.f);
          const float var = ts2 * (1.f / 256.f) - mu * mu;
          const float inv = rsqrtf(var + 1e-5f);
          out[(size_t)(g0 + j) * 256 + t] = (x - mu) * inv * gamma[t] + beta[t];
        }
        __builtin_amdgcn_s_barrier();  // redS consumed before next j overwrites
      }
      flushed = curg;
    }

    __builtin_amdgcn_s_barrier();  // all waves done reading As[c&1]
    if (c + 2 < nc) stage(c + 2, c & 1);
    if (c + 1 < nc) {
      if (c + 2 < nc)
        asm volatile("s_waitcnt vmcnt(8)" ::: "memory");  // stage(c+1) retired
      else
        asm volatile("s_waitcnt vmcnt(0)" ::: "memory");
      __builtin_amdgcn_s_barrier();  // As[(c+1)&1] published
    }
  }
}

extern "C" void kernel_launch(void* const* d_in, const int* in_sizes, int n_in,
                              void* d_out, int out_size, void* d_ws, size_t ws_size,
                              hipStream_t stream) {
  const float* f_node   = (const float*)d_in[0];
  const float* key_W    = (const float*)d_in[1];
  const float* key_b    = (const float*)d_in[2];
  const float* value_W  = (const float*)d_in[3];
  const float* value_b  = (const float*)d_in[4];
  const float* gamma    = (const float*)d_in[5];
  const float* beta     = (const float*)d_in[6];
  const int*   graph_id = (const int*)d_in[7];
  const int L = in_sizes[0] / 256;
  const int G = out_size / 256;

  char* ws = (char*)d_ws;
  size_t off = 0;
  int* order = (int*)(ws + off); off += (size_t)L * 4;
  off = (off + 255) & ~(size_t)255;
  int* counts = (int*)(ws + off); off += (size_t)G * 4;
  int* offsets = (int*)(ws + off); off += (size_t)(G + 1) * 4;
  int* cursor = (int*)(ws + off); off += (size_t)G * 4;
  off = (off + 255) & ~(size_t)255;
  unsigned short* W2 = (unsigned short*)(ws + off); off += 512 * 256 * 2;

  hipMemsetAsync(counts, 0, (size_t)G * 4, stream);
  k_hist<<<(L + 255) / 256, 256, 0, stream>>>(graph_id, L, counts);
  k_scan<<<1, 1024, 0, stream>>>(counts, offsets, cursor, G);
  k_scatter<<<(L + 255) / 256, 256, 0, stream>>>(graph_id, L, cursor, order);
  k_prepw<<<512, 256, 0, stream>>>(key_W, value_W, W2);
  const int nblk = (G + GPB - 1) / GPB;
  k_fused<<<nblk, 512, 0, stream>>>(f_node, W2, key_b, value_b, gamma, beta, order,
                                    offsets, (float*)d_out, L, G);
}